// Round 1
// 72.170 us; speedup vs baseline: 1.0135x; 1.0135x over previous
//
#include <hip/hip_runtime.h>
#include <cmath>

#define T_LEN 8192
#define B_ROWS 128
#define ND 360          // MAX_DELAY - MIN_DELAY
#define MIN_DELAY_C 60
#define BLOCK 256       // 4 waves: all load/store, wave 0 runs the serial chain

// ---- chain for C < 64 (p in {0,1,2} or wrap p=359): chunk width = C, partial wave ----
__device__ __forceinline__ void chain_small(float* __restrict__ y, int Wc,
                                            int lagA, int lagB,
                                            float a1, float a2, int lane) {
    for (int pos = 0; pos < T_LEN; pos += Wc) {
        int end = pos + Wc; if (end > T_LEN) end = T_LEN;
        int j = pos + lane;
        if (j < end) {
            float ya = (j >= lagA) ? y[j - lagA] : 0.0f;
            float yb = (j >= lagB) ? y[j - lagB] : 0.0f;
            y[j] = y[j] - a1 * ya - a2 * yb;
        }
        // wave-synchronous: DS ops from one wave complete in order; just pin
        // the compiler's schedule so next chunk's reads stay after these writes.
        __builtin_amdgcn_sched_barrier(0);
    }
}

// ---- chain with chunk width 64*K <= min(lagA,lagB): one wave, no block barriers ----
// All reads of a chunk are issued before all writes (chunk reads can never alias
// chunk writes since W <= min lag), so there is ~one lgkmcnt wait per chunk.
template<int K>
__device__ __forceinline__ void chain_k(float* __restrict__ y,
                                        int lagA, int lagB,
                                        float a1, float a2, int lane) {
    constexpr int W = 64 * K;
    for (int pos = 0; pos < T_LEN; pos += W) {
        float v[K];
#pragma unroll
        for (int s = 0; s < K; ++s) {
            int j = pos + lane + 64 * s;
            if (j < T_LEN) {
                float ya = (j >= lagA) ? y[j - lagA] : 0.0f;
                float yb = (j >= lagB) ? y[j - lagB] : 0.0f;
                v[s] = y[j] - a1 * ya - a2 * yb;
            } else {
                v[s] = 0.0f;
            }
        }
#pragma unroll
        for (int s = 0; s < K; ++s) {
            int j = pos + lane + 64 * s;
            if (j < T_LEN) y[j] = v[s];
        }
        __builtin_amdgcn_sched_barrier(0);
    }
}

__global__ __launch_bounds__(BLOCK) void ks_resonator_kernel(
    const float* __restrict__ excitation,     // (128,1,8192)
    const float* __restrict__ gumbel,         // (360,)
    const float* __restrict__ delay_param,    // (360,)
    const float* __restrict__ feedback_gain,  // (1,)
    const float* __restrict__ refl,           // (2,)
    float* __restrict__ out)                  // (128,1,8192)
{
    __shared__ float y[T_LEN];                // 32 KB row buffer (in-place x -> y)
    __shared__ float red_v[BLOCK];
    __shared__ int   red_i[BLOCK];
    __shared__ float s_a1, s_a2;
    __shared__ int   s_lagA, s_lagB;

    const int tid = threadIdx.x;
    const int row = blockIdx.x;

    // ---- load excitation row into LDS (float4, all 4 waves) ----
    const float4* __restrict__ x4 = (const float4*)(excitation + (size_t)row * T_LEN);
    float4* y4 = (float4*)y;
    for (int i = tid; i < T_LEN / 4; i += BLOCK) y4[i] = x4[i];

    // ---- redundant per-block argmax over (delay_param + gumbel), 360 elems ----
    float v = -INFINITY; int idx = 0;
    if (tid < ND) { v = delay_param[tid] + gumbel[tid]; idx = tid; }
    if (tid + BLOCK < ND) {
        float v2 = delay_param[tid + BLOCK] + gumbel[tid + BLOCK];
        if (v2 > v) { v = v2; idx = tid + BLOCK; }   // higher index: strict > only
    }
    red_v[tid] = v; red_i[tid] = idx;
    __syncthreads();
    for (int off = BLOCK / 2; off > 0; off >>= 1) {
        if (tid < off) {
            float v2 = red_v[tid + off]; int i2 = red_i[tid + off];
            float v1 = red_v[tid];       int i1 = red_i[tid];
            // jnp.argmax: first occurrence wins ties
            if (v2 > v1 || (v2 == v1 && i2 < i1)) { red_v[tid] = v2; red_i[tid] = i2; }
        }
        __syncthreads();
    }

    if (tid == 0) {
        int p = red_i[0];
        // rc = tanh(reflection_coeffs); k = resonant_activation(rc, 0) = tanh(rc)
        float k1 = tanhf(tanhf(refl[0]));
        float k2 = tanhf(tanhf(refl[1]));
        float a1 = k1 * (1.0f - k2);
        float a2 = fminf(fmaxf(k2, -0.999f), 0.999f);
        float bound = 0.999f - fabsf(a2);
        a1 = fminf(fmaxf(a1, -bound), bound);
        float fg = feedback_gain[0];
        float g = powf(1.0f / (1.0f + expf(-fg)), 0.45f);
        a1 *= g; a2 *= g;
        int p2 = (p + 1) % ND;           // jnp.roll(one_hot, 1)
        s_a1 = a1; s_a2 = a2;
        s_lagA = MIN_DELAY_C + p + 1;    // coeff at 60+p multiplies y[t-1-(60+p)]
        s_lagB = MIN_DELAY_C + p2 + 1;
    }
    __syncthreads();   // also guarantees the row load (vm+ds) has drained

    const float a1 = s_a1, a2 = s_a2;
    const int lagA = s_lagA, lagB = s_lagB;
    const int C = (lagA < lagB) ? lagA : lagB;   // 61..420

    // ---- serial chain: ONE wave, zero block barriers inside ----
    if (tid < 64) {
        const int lane = tid;
        if (C < 64) {
            chain_small(y, C, lagA, lagB, a1, a2, lane);
        } else {
            switch (C >> 6) {            // floor(C/64) in 1..6
                case 1:  chain_k<1>(y, lagA, lagB, a1, a2, lane); break;
                case 2:  chain_k<2>(y, lagA, lagB, a1, a2, lane); break;
                case 3:  chain_k<3>(y, lagA, lagB, a1, a2, lane); break;
                case 4:  chain_k<4>(y, lagA, lagB, a1, a2, lane); break;
                case 5:  chain_k<5>(y, lagA, lagB, a1, a2, lane); break;
                default: chain_k<6>(y, lagA, lagB, a1, a2, lane); break;
            }
        }
    }
    __syncthreads();

    // ---- store (float4, all 4 waves) ----
    float4* __restrict__ o4 = (float4*)(out + (size_t)row * T_LEN);
    for (int i = tid; i < T_LEN / 4; i += BLOCK) o4[i] = y4[i];
}

extern "C" void kernel_launch(void* const* d_in, const int* in_sizes, int n_in,
                              void* d_out, int out_size, void* d_ws, size_t ws_size,
                              hipStream_t stream) {
    const float* excitation    = (const float*)d_in[0];
    const float* gumbel        = (const float*)d_in[1];
    const float* delay_param   = (const float*)d_in[2];
    const float* feedback_gain = (const float*)d_in[3];
    const float* refl          = (const float*)d_in[4];
    float* out = (float*)d_out;

    ks_resonator_kernel<<<B_ROWS, BLOCK, 0, stream>>>(
        excitation, gumbel, delay_param, feedback_gain, refl, out);
}